// Round 1
// baseline (197.866 us; speedup 1.0000x reference)
//
#include <hip/hip_runtime.h>
#include <hip/hip_bf16.h>

#define NN 50000
#define NPAD 50048           // 64-row padded for MFMA grid
#define NE 800000
#define NF 128
#define HH 96
#define TF 10
#define Z1DIM (HH + TF)   // 106
#define ZK 128            // padded K for layer-1 MFMA
#define NCH 4             // column chunks for the gather
#define CW 24             // chunk width (cols): NCH*CW == HH
#define NBK 196           // dst buckets of 256 nodes
#define CAP 5120          // per-bucket temp capacity
#define EPB 4096          // edges per fillA block (was 8192; 2x blocks)
#define FILLA_B ((NE + EPB - 1) / EPB)   // 196

typedef __attribute__((ext_vector_type(8))) short short8;
typedef __attribute__((ext_vector_type(8))) unsigned short ushort8;
typedef __attribute__((ext_vector_type(4))) float f32x4;

__device__ __forceinline__ float bu2f(unsigned short u) {
    union { unsigned int i; float f; } c;
    c.i = ((unsigned int)u) << 16;
    return c.f;
}
__device__ __forceinline__ unsigned short f2bu(float f) {
    union { __hip_bfloat16 h; unsigned short u; } c;
    c.h = __float2bfloat16(f);
    return c.u;
}

// ---- kernel 1: zero deg[NN]; bcur[b] = b*CAP; off[NN] = NE ----
__global__ void k_init(int* __restrict__ bcur, int* __restrict__ off,
                       int* __restrict__ deg) {
    int i = blockIdx.x * 256 + threadIdx.x;
    if (i < NN) deg[i] = 0;
    if (i < NBK) bcur[i] = i * CAP;
    if (i == NN) off[NN] = NE;
}

// ---- kernel 2: fused {edge binning + deg histogram} | {weight transpose, zb tail} ----
#define WBLK (NF * HH / 4 / 256)       // 12
#define W1BLK (HH * ZK / 4 / 256)      // 12
#define ZTBLK (NPAD / 32)              // 1564
#define ZPBLK 5
__global__ __launch_bounds__(256) void k_pre(const int* __restrict__ ei,
                                             int* __restrict__ bcur,
                                             int* __restrict__ temp,
                                             int* __restrict__ deg,
                                             const float* __restrict__ W,
                                             const float* __restrict__ W1,
                                             const float* __restrict__ tmp,
                                             unsigned short* __restrict__ Wt,
                                             unsigned short* __restrict__ Wt1,
                                             unsigned short* __restrict__ zb) {
    const int t = threadIdx.x;
    if (blockIdx.x < FILLA_B) {
        // ---- fillA: bin edges into 196 dst-range buckets, histogram deg ----
        __shared__ int hist[NBK], bas[NBK];
        for (int m = t; m < NBK; m += 256) hist[m] = 0;
        __syncthreads();
        const int e0 = blockIdx.x * EPB;
        const int ecap = min(e0 + EPB, NE);
        for (int e = e0 + t; e < ecap; e += 256) {
            int d = ei[NE + e];
            atomicAdd(&hist[d >> 8], 1);
            atomicAdd(&deg[d], 1);
        }
        __syncthreads();
        for (int m = t; m < NBK; m += 256) {
            int c = hist[m];
            bas[m] = c ? atomicAdd(&bcur[m], c) : 0;
            hist[m] = 0;   // reuse as run cursor
        }
        __syncthreads();
        for (int e = e0 + t; e < ecap; e += 256) {
            int d = ei[NE + e], s = ei[e];
            int b = d >> 8;
            int r = atomicAdd(&hist[b], 1);
            temp[bas[b] + r] = ((d & 255) << 16) | s;
        }
        return;
    }
    // ---- prep: Wt, Wt1, zb tail (cols 96..128 + pad rows) ----
    int b = blockIdx.x - FILLA_B;
    if (b < WBLK) {
        int e = (b * 256 + t) * 4;
        int n = e >> 7, k = e & 127;
        ushort4 v;
        v.x = f2bu(W[(k + 0) * HH + n]);
        v.y = f2bu(W[(k + 1) * HH + n]);
        v.z = f2bu(W[(k + 2) * HH + n]);
        v.w = f2bu(W[(k + 3) * HH + n]);
        *(ushort4*)(Wt + e) = v;
    } else if (b < WBLK + W1BLK) {
        int e = ((b - WBLK) * 256 + t) * 4;
        int n = e >> 7, k = e & 127;     // n in [0,96), k in [0,128)
        ushort4 v;
        v.x = (k + 0 < Z1DIM) ? f2bu(W1[(k + 0) * HH + n]) : (unsigned short)0;
        v.y = (k + 1 < Z1DIM) ? f2bu(W1[(k + 1) * HH + n]) : (unsigned short)0;
        v.z = (k + 2 < Z1DIM) ? f2bu(W1[(k + 2) * HH + n]) : (unsigned short)0;
        v.w = (k + 3 < Z1DIM) ? f2bu(W1[(k + 3) * HH + n]) : (unsigned short)0;
        *(ushort4*)(Wt1 + e) = v;
    } else if (b < WBLK + W1BLK + ZTBLK) {
        // zb cols [96,128): temporal (cc<10) else 0
        int t4 = ((b - WBLK - W1BLK) * 256 + t) * 4;
        int i = t4 >> 5, cc = t4 & 31;
        ushort4 v; v.x = v.y = v.z = v.w = 0;
        if (i < NN) {
            if (cc + 0 < TF) v.x = f2bu(tmp[(size_t)i * TF + cc + 0]);
            if (cc + 1 < TF) v.y = f2bu(tmp[(size_t)i * TF + cc + 1]);
            if (cc + 2 < TF) v.z = f2bu(tmp[(size_t)i * TF + cc + 2]);
            if (cc + 3 < TF) v.w = f2bu(tmp[(size_t)i * TF + cc + 3]);
        }
        *(ushort4*)(zb + (size_t)i * ZK + HH + cc) = v;
    } else {
        // zb pad rows [NN,NPAD), cols [0,96): zero
        int t4 = ((b - WBLK - W1BLK - ZTBLK) * 256 + t) * 4;
        if (t4 < (NPAD - NN) * HH) {
            int i = NN + t4 / HH, j = t4 % HH;
            ushort4 z; z.x = z.y = z.z = z.w = 0;
            *(ushort4*)(zb + (size_t)i * ZK + j) = z;
        }
    }
}

// ---- kernel 3: fused {per-bucket sort -> csr/off} | {MFMA GEMM + x·W2 row-dot} ----
__global__ __launch_bounds__(256) void k_gg(const int* __restrict__ temp,
                                            const int* __restrict__ bcur,
                                            unsigned short* __restrict__ csr,
                                            int* __restrict__ off,
                                            const float* __restrict__ x,
                                            const unsigned short* __restrict__ Wt,
                                            const float* __restrict__ W2,
                                            const int* __restrict__ deg,
                                            unsigned short* __restrict__ hp_c,
                                            float* __restrict__ xw2) {
    const int t = threadIdx.x;
    if (blockIdx.x < NBK) {
        // ---- fillB: per-bucket local sort -> csr(ushort), off ----
        __shared__ int ls[256], lc[256];
        const int b = blockIdx.x;
        int szt = (t < NBK) ? (bcur[t] - t * CAP) : 0;
        ls[t] = szt;
        __syncthreads();
#pragma unroll
        for (int d = 1; d < 256; d <<= 1) {
            int u = (t >= d) ? ls[t - d] : 0;
            __syncthreads();
            ls[t] += u;
            __syncthreads();
        }
        const int g0 = (b > 0) ? ls[b - 1] : 0;
        __syncthreads();
        ls[t] = 0;
        __syncthreads();
        const int seg0 = b * CAP;
        const int m = bcur[b] - seg0;
        for (int k = t; k < m; k += 256) atomicAdd(&ls[temp[seg0 + k] >> 16], 1);
        __syncthreads();
        const int myc = ls[t];
        lc[t] = myc;
        __syncthreads();
#pragma unroll
        for (int d = 1; d < 256; d <<= 1) {
            int u = (t >= d) ? lc[t - d] : 0;
            __syncthreads();
            lc[t] += u;
            __syncthreads();
        }
        const int myoff = lc[t] - myc;    // exclusive within bucket
        __syncthreads();
        lc[t] = myoff;                    // cursor
        const int i = b * 256 + t;
        if (i < NN) off[i] = g0 + myoff;
        __syncthreads();
        for (int k = t; k < m; k += 256) {
            int v = temp[seg0 + k];
            int r = atomicAdd(&lc[v >> 16], 1);
            csr[g0 + r] = (unsigned short)(v & 0xFFFF);
        }
        return;
    }
    // ---- gemm: h = bf16(x)·Wt scaled by rsqrt(deg+1), + fused x·W2[96:224] ----
    const int wave = t >> 6;
    const int lane = t & 63;
    const int quad = lane >> 4;
    const int l16 = lane & 15;
    const int Mbase = (blockIdx.x - NBK) * 64 + wave * 16;
    const int row = Mbase + l16;
    const bool valid = row < NN;

    const float* xr = x + (size_t)row * NF + quad * 8;
    const unsigned short* brow = Wt + (size_t)l16 * NF + quad * 8;

    f32x4 acc[6] = {};
    float xs = 0.f;
#pragma unroll
    for (int ks = 0; ks < 4; ++ks) {
        short8 a = {};
        if (valid) {
            float4 f0 = *(const float4*)(xr + ks * 32);
            float4 f1 = *(const float4*)(xr + ks * 32 + 4);
            const float4 w0 = *(const float4*)(W2 + HH + quad * 8 + ks * 32);
            const float4 w1 = *(const float4*)(W2 + HH + quad * 8 + ks * 32 + 4);
            xs = fmaf(f0.x, w0.x, xs); xs = fmaf(f0.y, w0.y, xs);
            xs = fmaf(f0.z, w0.z, xs); xs = fmaf(f0.w, w0.w, xs);
            xs = fmaf(f1.x, w1.x, xs); xs = fmaf(f1.y, w1.y, xs);
            xs = fmaf(f1.z, w1.z, xs); xs = fmaf(f1.w, w1.w, xs);
            a[0] = (short)f2bu(f0.x); a[1] = (short)f2bu(f0.y);
            a[2] = (short)f2bu(f0.z); a[3] = (short)f2bu(f0.w);
            a[4] = (short)f2bu(f1.x); a[5] = (short)f2bu(f1.y);
            a[6] = (short)f2bu(f1.z); a[7] = (short)f2bu(f1.w);
        }
#pragma unroll
        for (int nt = 0; nt < 6; ++nt) {
            short8 bfrag = *(const short8*)(brow + (size_t)nt * 16 * NF + ks * 32);
            acc[nt] = __builtin_amdgcn_mfma_f32_16x16x32_bf16(a, bfrag, acc[nt], 0, 0, 0);
        }
    }
    xs += __shfl_xor(xs, 16, 64);
    xs += __shfl_xor(xs, 32, 64);
    if (quad == 0 && valid) xw2[row] = xs;

    const int r0 = Mbase + quad * 4;
    float dv[4];
#pragma unroll
    for (int k = 0; k < 4; ++k) {
        int r = r0 + k;
        dv[k] = (r < NN) ? rsqrtf((float)deg[r] + 1.f) : 0.f;
    }
#pragma unroll
    for (int nt = 0; nt < 6; ++nt) {
        int n = nt * 16 + l16;
        int c = n / CW, jj = n - c * CW;
        unsigned short* dst = hp_c + (size_t)c * NN * CW + jj;
#pragma unroll
        for (int k = 0; k < 4; ++k)
            if (r0 + k < NN) dst[(size_t)(r0 + k) * CW] = f2bu(acc[nt][k] * dv[k]);
    }
}

// ---- kernel 4: chunked gather-aggregate -> zb[i][0..96), XCD-affine ----
// One thread owns ALL 24 cols of a chunk for (node, half). Per edge per chunk:
// 1 csr load + 3x16B data loads (was 3 csr + 3 data across q-split threads).
// Adjacent lanes take contiguous halves of the edge range; combine via shfl_xor(1).
#define RPC2 196                // (b>>3) range; r = 2*(b>>3)+(slot&1) covers 392 rows
#define AGGB (8 * RPC2)         // 1568 blocks
__global__ __launch_bounds__(256) void k_agg(const unsigned short* __restrict__ hp_c,
                                             const int* __restrict__ off,
                                             const unsigned short* __restrict__ csr,
                                             const float* __restrict__ bg,
                                             unsigned short* __restrict__ zb) {
    const int b = blockIdx.x;
    const int slot = b & 7;
    const int c = slot >> 1;                       // chunk: pinned to XCD pair
    const int r = (b >> 3) * 2 + (slot & 1);
    const int item = r * 256 + threadIdx.x;
    if (item >= NN * 2) return;
    const int i = item >> 1;
    const int h = item & 1;                        // half (== lane parity)
    const unsigned short* __restrict__ base = hp_c + (size_t)c * NN * CW;

    float a[CW];
    if (h == 0) {  // self-loop term on even half only
        const unsigned short* sp = base + (size_t)i * CW;
        ushort8 s0 = *(const ushort8*)(sp);
        ushort8 s1 = *(const ushort8*)(sp + 8);
        ushort8 s2 = *(const ushort8*)(sp + 16);
#pragma unroll
        for (int j = 0; j < 8; ++j) {
            a[j] = bu2f(s0[j]); a[8 + j] = bu2f(s1[j]); a[16 + j] = bu2f(s2[j]);
        }
    } else {
#pragma unroll
        for (int j = 0; j < CW; ++j) a[j] = 0.f;
    }

    const int start = off[i];
    const int end = off[i + 1];
    const int len = end - start;
    const float dv = rsqrtf((float)len + 1.f);
    const int half0 = (len + 1) >> 1;
    int k = h ? start + half0 : start;
    const int ke = h ? end : start + half0;
    for (; k + 1 < ke; k += 2) {   // 2 edges x 3 loads in flight
        const unsigned short* p0 = base + (size_t)csr[k] * CW;
        const unsigned short* p1 = base + (size_t)csr[k + 1] * CW;
        ushort8 v0 = *(const ushort8*)(p0);
        ushort8 v1 = *(const ushort8*)(p0 + 8);
        ushort8 v2 = *(const ushort8*)(p0 + 16);
        ushort8 w0 = *(const ushort8*)(p1);
        ushort8 w1 = *(const ushort8*)(p1 + 8);
        ushort8 w2 = *(const ushort8*)(p1 + 16);
#pragma unroll
        for (int j = 0; j < 8; ++j) {
            a[j]      += bu2f(v0[j]) + bu2f(w0[j]);
            a[8 + j]  += bu2f(v1[j]) + bu2f(w1[j]);
            a[16 + j] += bu2f(v2[j]) + bu2f(w2[j]);
        }
    }
    if (k < ke) {
        const unsigned short* p0 = base + (size_t)csr[k] * CW;
        ushort8 v0 = *(const ushort8*)(p0);
        ushort8 v1 = *(const ushort8*)(p0 + 8);
        ushort8 v2 = *(const ushort8*)(p0 + 16);
#pragma unroll
        for (int j = 0; j < 8; ++j) {
            a[j] += bu2f(v0[j]); a[8 + j] += bu2f(v1[j]); a[16 + j] += bu2f(v2[j]);
        }
    }
#pragma unroll
    for (int j = 0; j < CW; ++j) a[j] += __shfl_xor(a[j], 1, 64);
    if (h == 0) {
        const int j0 = c * CW;
        ushort8 o0, o1, o2;
#pragma unroll
        for (int j = 0; j < 8; ++j) {
            o0[j] = f2bu(fmaxf(fmaf(dv, a[j],      bg[j0 + j]),      0.f));
            o1[j] = f2bu(fmaxf(fmaf(dv, a[8 + j],  bg[j0 + 8 + j]),  0.f));
            o2[j] = f2bu(fmaxf(fmaf(dv, a[16 + j], bg[j0 + 16 + j]), 0.f));
        }
        unsigned short* zp = zb + (size_t)i * ZK + j0;
        *(ushort8*)(zp) = o0;
        *(ushort8*)(zp + 8) = o1;
        *(ushort8*)(zp + 16) = o2;
    }
}

// ---- kernel 5: MFMA layer-1 + fused layer-2 epilogue ----
__global__ __launch_bounds__(256) void k_mlp2(const unsigned short* __restrict__ zb,
                                              const unsigned short* __restrict__ Wt1,
                                              const float* __restrict__ b1,
                                              const float* __restrict__ W2,
                                              const float* __restrict__ b2,
                                              const float* __restrict__ xw2,
                                              float* __restrict__ out) {
    const int wave = threadIdx.x >> 6;
    const int lane = threadIdx.x & 63;
    const int quad = lane >> 4;
    const int l16 = lane & 15;
    const int Mbase = blockIdx.x * 64 + wave * 16;

    const unsigned short* arow = zb + (size_t)(Mbase + l16) * ZK + quad * 8;
    const unsigned short* brow = Wt1 + (size_t)l16 * ZK + quad * 8;

    f32x4 acc[6] = {};
#pragma unroll
    for (int ks = 0; ks < 4; ++ks) {
        short8 a = *(const short8*)(arow + ks * 32);
#pragma unroll
        for (int nt = 0; nt < 6; ++nt) {
            short8 bfrag = *(const short8*)(brow + (size_t)nt * 16 * ZK + ks * 32);
            acc[nt] = __builtin_amdgcn_mfma_f32_16x16x32_bf16(a, bfrag, acc[nt], 0, 0, 0);
        }
    }
    float bb[6], wa[6];
#pragma unroll
    for (int nt = 0; nt < 6; ++nt) {
        int c = nt * 16 + l16;
        bb[nt] = b1[c];
        wa[nt] = W2[c];
    }
    const float bias2 = b2[0];

#pragma unroll
    for (int reg = 0; reg < 4; ++reg) {
        const int r = Mbase + quad * 4 + reg;
        float p = 0.f;
#pragma unroll
        for (int nt = 0; nt < 6; ++nt)
            p = fmaf(fmaxf(acc[nt][reg] + bb[nt], 0.f), wa[nt], p);
#pragma unroll
        for (int m = 1; m < 16; m <<= 1) p += __shfl_xor(p, m, 64);
        if (l16 == 0 && r < NN) out[r] = fmaxf(p + xw2[r] + bias2, 0.f);
    }
}

extern "C" void kernel_launch(void* const* d_in, const int* in_sizes, int n_in,
                              void* d_out, int out_size, void* d_ws, size_t ws_size,
                              hipStream_t stream) {
    const float* x   = (const float*)d_in[0];
    const int*   ei  = (const int*)d_in[1];
    const float* tmp = (const float*)d_in[2];
    const float* Wg  = (const float*)d_in[3];
    const float* bg  = (const float*)d_in[4];
    const float* W1  = (const float*)d_in[5];
    const float* b1  = (const float*)d_in[6];
    const float* W2  = (const float*)d_in[7];
    const float* b2  = (const float*)d_in[8];
    float* out = (float*)d_out;

    char* base = (char*)d_ws;
    int* off  = (int*)base;                                   // NN+1 ints (256KB slot)
    int* bcur = (int*)(base + (256 << 10));                   // 196 ints
    int* deg  = (int*)(base + (260 << 10));                   // NN ints (200KB)
    unsigned short* csr = (unsigned short*)(base + (512 << 10));       // NE ushort = 1.6MB
    unsigned short* Wt  = (unsigned short*)(base + ((size_t)3 << 20)); // NF*HH bf16
    unsigned short* Wt1 = Wt + NF * HH;                       // HH*ZK bf16
    unsigned short* hp_c = (unsigned short*)(base + ((size_t)4 << 20));  // NN*HH bf16 = 9.6MB
    unsigned short* zb  = (unsigned short*)(base + ((size_t)14 << 20));  // NPAD*ZK bf16 = 12.8MB
    float* xw2 = (float*)(base + ((size_t)27 << 20));         // NPAD floats
    int* temp  = (int*)(base + ((size_t)28 << 20));           // 196*CAP ints = 4.01MB (no alias now)

    k_init <<<(NN + 256) / 256, 256, 0, stream>>>(bcur, off, deg);
    k_pre  <<<FILLA_B + WBLK + W1BLK + ZTBLK + ZPBLK, 256, 0, stream>>>(
                ei, bcur, temp, deg, Wg, W1, tmp, Wt, Wt1, zb);
    k_gg   <<<NBK + NPAD / 64, 256, 0, stream>>>(temp, bcur, csr, off, x, Wt, W2, deg, hp_c, xw2);
    k_agg  <<<AGGB, 256, 0, stream>>>(hp_c, off, csr, bg, zb);
    k_mlp2 <<<NPAD / 64, 256, 0, stream>>>(zb, Wt1, b1, W2, b2, xw2, out);
}

// Round 2
// 173.985 us; speedup vs baseline: 1.1373x; 1.1373x over previous
//
#include <hip/hip_runtime.h>
#include <hip/hip_bf16.h>

#define NN 50000
#define NPAD 50048           // 64-row padded for MFMA grid
#define NE 800000
#define NF 128
#define HH 96
#define TF 10
#define Z1DIM (HH + TF)   // 106
#define ZK 128            // padded K for layer-1 MFMA
#define NCH 4             // column chunks for the gather
#define CW 24             // chunk width (cols): NCH*CW == HH
#define NBK 196           // dst buckets of 256 nodes
#define CAP 5120          // per-bucket temp capacity
#define EPB 4096          // edges per fillA block
#define FILLA_B ((NE + EPB - 1) / EPB)   // 196

typedef __attribute__((ext_vector_type(8))) short short8;
typedef __attribute__((ext_vector_type(8))) unsigned short ushort8;
typedef __attribute__((ext_vector_type(4))) float f32x4;

__device__ __forceinline__ float bu2f(unsigned short u) {
    union { unsigned int i; float f; } c;
    c.i = ((unsigned int)u) << 16;
    return c.f;
}
__device__ __forceinline__ unsigned short f2bu(float f) {
    union { __hip_bfloat16 h; unsigned short u; } c;
    c.h = __float2bfloat16(f);
    return c.u;
}

// ---- kernel 1: bcur[b] = b*CAP; off[NN] = NE ----
__global__ void k_init(int* __restrict__ bcur, int* __restrict__ off) {
    int t = threadIdx.x;
    if (t < NBK) bcur[t] = t * CAP;
    if (t == 255) off[NN] = NE;
}

// ---- kernel 2: fused {edge binning (no deg atomics)} | {weight transpose, zb tail} ----
#define WBLK (NF * HH / 4 / 256)       // 12
#define W1BLK (HH * ZK / 4 / 256)      // 12
#define ZTBLK (NPAD / 32)              // 1564
#define ZPBLK 5
__global__ __launch_bounds__(256) void k_pre(const int* __restrict__ ei,
                                             int* __restrict__ bcur,
                                             int* __restrict__ temp,
                                             const float* __restrict__ W,
                                             const float* __restrict__ W1,
                                             const float* __restrict__ tmp,
                                             unsigned short* __restrict__ Wt,
                                             unsigned short* __restrict__ Wt1,
                                             unsigned short* __restrict__ zb) {
    const int t = threadIdx.x;
    if (blockIdx.x < FILLA_B) {
        // ---- fillA: bin edges into 196 dst-range buckets ----
        __shared__ int hist[NBK], bas[NBK];
        for (int m = t; m < NBK; m += 256) hist[m] = 0;
        __syncthreads();
        const int e0 = blockIdx.x * EPB;
        const int ecap = min(e0 + EPB, NE);
        for (int e = e0 + t; e < ecap; e += 256) {
            int d = ei[NE + e];
            atomicAdd(&hist[d >> 8], 1);
        }
        __syncthreads();
        for (int m = t; m < NBK; m += 256) {
            int c = hist[m];
            bas[m] = c ? atomicAdd(&bcur[m], c) : 0;
            hist[m] = 0;   // reuse as run cursor
        }
        __syncthreads();
        for (int e = e0 + t; e < ecap; e += 256) {
            int d = ei[NE + e], s = ei[e];
            int b = d >> 8;
            int r = atomicAdd(&hist[b], 1);
            temp[bas[b] + r] = ((d & 255) << 16) | s;
        }
        return;
    }
    // ---- prep: Wt, Wt1, zb tail (cols 96..128 + pad rows) ----
    int b = blockIdx.x - FILLA_B;
    if (b < WBLK) {
        int e = (b * 256 + t) * 4;
        int n = e >> 7, k = e & 127;
        ushort4 v;
        v.x = f2bu(W[(k + 0) * HH + n]);
        v.y = f2bu(W[(k + 1) * HH + n]);
        v.z = f2bu(W[(k + 2) * HH + n]);
        v.w = f2bu(W[(k + 3) * HH + n]);
        *(ushort4*)(Wt + e) = v;
    } else if (b < WBLK + W1BLK) {
        int e = ((b - WBLK) * 256 + t) * 4;
        int n = e >> 7, k = e & 127;     // n in [0,96), k in [0,128)
        ushort4 v;
        v.x = (k + 0 < Z1DIM) ? f2bu(W1[(k + 0) * HH + n]) : (unsigned short)0;
        v.y = (k + 1 < Z1DIM) ? f2bu(W1[(k + 1) * HH + n]) : (unsigned short)0;
        v.z = (k + 2 < Z1DIM) ? f2bu(W1[(k + 2) * HH + n]) : (unsigned short)0;
        v.w = (k + 3 < Z1DIM) ? f2bu(W1[(k + 3) * HH + n]) : (unsigned short)0;
        *(ushort4*)(Wt1 + e) = v;
    } else if (b < WBLK + W1BLK + ZTBLK) {
        // zb cols [96,128): temporal (cc<10) else 0
        int t4 = ((b - WBLK - W1BLK) * 256 + t) * 4;
        int i = t4 >> 5, cc = t4 & 31;
        ushort4 v; v.x = v.y = v.z = v.w = 0;
        if (i < NN) {
            if (cc + 0 < TF) v.x = f2bu(tmp[(size_t)i * TF + cc + 0]);
            if (cc + 1 < TF) v.y = f2bu(tmp[(size_t)i * TF + cc + 1]);
            if (cc + 2 < TF) v.z = f2bu(tmp[(size_t)i * TF + cc + 2]);
            if (cc + 3 < TF) v.w = f2bu(tmp[(size_t)i * TF + cc + 3]);
        }
        *(ushort4*)(zb + (size_t)i * ZK + HH + cc) = v;
    } else {
        // zb pad rows [NN,NPAD), cols [0,96): zero
        int t4 = ((b - WBLK - W1BLK - ZTBLK) * 256 + t) * 4;
        if (t4 < (NPAD - NN) * HH) {
            int i = NN + t4 / HH, j = t4 % HH;
            ushort4 z; z.x = z.y = z.z = z.w = 0;
            *(ushort4*)(zb + (size_t)i * ZK + j) = z;
        }
    }
}

// ---- kernel 3: per-bucket histogram + scans -> off[] only (cheap half of fillB) ----
__global__ __launch_bounds__(256) void k_off(const int* __restrict__ temp,
                                             const int* __restrict__ bcur,
                                             int* __restrict__ off) {
    __shared__ int ls[256], lc[256];
    const int b = blockIdx.x, t = threadIdx.x;
    // exclusive scan of all bucket sizes -> this bucket's global base g0
    int szt = (t < NBK) ? (bcur[t] - t * CAP) : 0;
    ls[t] = szt;
    __syncthreads();
#pragma unroll
    for (int d = 1; d < 256; d <<= 1) {
        int u = (t >= d) ? ls[t - d] : 0;
        __syncthreads();
        ls[t] += u;
        __syncthreads();
    }
    const int g0 = (b > 0) ? ls[b - 1] : 0;
    __syncthreads();
    ls[t] = 0;
    __syncthreads();
    const int seg0 = b * CAP;
    const int m = bcur[b] - seg0;
    for (int k = t; k < m; k += 256) atomicAdd(&ls[temp[seg0 + k] >> 16], 1);
    __syncthreads();
    const int myc = ls[t];
    lc[t] = myc;
    __syncthreads();
#pragma unroll
    for (int d = 1; d < 256; d <<= 1) {
        int u = (t >= d) ? lc[t - d] : 0;
        __syncthreads();
        lc[t] += u;
        __syncthreads();
    }
    const int i = b * 256 + t;
    if (i < NN) off[i] = g0 + lc[t] - myc;
}

// ---- kernel 4: fused {csr scatter-sort (reads off)} | {MFMA GEMM + x·W2 row-dot} ----
__global__ __launch_bounds__(256) void k_gg(const int* __restrict__ temp,
                                            const int* __restrict__ bcur,
                                            unsigned short* __restrict__ csr,
                                            const int* __restrict__ off,
                                            const float* __restrict__ x,
                                            const unsigned short* __restrict__ Wt,
                                            const float* __restrict__ W2,
                                            unsigned short* __restrict__ hp_c,
                                            float* __restrict__ xw2) {
    const int t = threadIdx.x;
    if (blockIdx.x < NBK) {
        // ---- sort: scatter bucket entries to csr at absolute cursors off[i] ----
        __shared__ int lc[256];
        const int b = blockIdx.x;
        const int i = b * 256 + t;
        lc[t] = (i < NN) ? off[i] : 0;
        __syncthreads();
        const int seg0 = b * CAP;
        const int m = bcur[b] - seg0;
        for (int k = t; k < m; k += 256) {
            int v = temp[seg0 + k];
            int r = atomicAdd(&lc[v >> 16], 1);
            csr[r] = (unsigned short)(v & 0xFFFF);
        }
        return;
    }
    // ---- gemm: h = bf16(x)·Wt scaled by rsqrt(deg+1), + fused x·W2[96:224] ----
    const int wave = t >> 6;
    const int lane = t & 63;
    const int quad = lane >> 4;
    const int l16 = lane & 15;
    const int Mbase = (blockIdx.x - NBK) * 64 + wave * 16;
    const int row = Mbase + l16;
    const bool valid = row < NN;

    const float* xr = x + (size_t)row * NF + quad * 8;
    const unsigned short* brow = Wt + (size_t)l16 * NF + quad * 8;

    f32x4 acc[6] = {};
    float xs = 0.f;
#pragma unroll
    for (int ks = 0; ks < 4; ++ks) {
        short8 a = {};
        if (valid) {
            float4 f0 = *(const float4*)(xr + ks * 32);
            float4 f1 = *(const float4*)(xr + ks * 32 + 4);
            const float4 w0 = *(const float4*)(W2 + HH + quad * 8 + ks * 32);
            const float4 w1 = *(const float4*)(W2 + HH + quad * 8 + ks * 32 + 4);
            xs = fmaf(f0.x, w0.x, xs); xs = fmaf(f0.y, w0.y, xs);
            xs = fmaf(f0.z, w0.z, xs); xs = fmaf(f0.w, w0.w, xs);
            xs = fmaf(f1.x, w1.x, xs); xs = fmaf(f1.y, w1.y, xs);
            xs = fmaf(f1.z, w1.z, xs); xs = fmaf(f1.w, w1.w, xs);
            a[0] = (short)f2bu(f0.x); a[1] = (short)f2bu(f0.y);
            a[2] = (short)f2bu(f0.z); a[3] = (short)f2bu(f0.w);
            a[4] = (short)f2bu(f1.x); a[5] = (short)f2bu(f1.y);
            a[6] = (short)f2bu(f1.z); a[7] = (short)f2bu(f1.w);
        }
#pragma unroll
        for (int nt = 0; nt < 6; ++nt) {
            short8 bfrag = *(const short8*)(brow + (size_t)nt * 16 * NF + ks * 32);
            acc[nt] = __builtin_amdgcn_mfma_f32_16x16x32_bf16(a, bfrag, acc[nt], 0, 0, 0);
        }
    }
    xs += __shfl_xor(xs, 16, 64);
    xs += __shfl_xor(xs, 32, 64);
    if (quad == 0 && valid) xw2[row] = xs;

    const int r0 = Mbase + quad * 4;
    float dv[4];
#pragma unroll
    for (int k = 0; k < 4; ++k) {
        int r = r0 + k;
        dv[k] = (r < NN) ? rsqrtf((float)(off[r + 1] - off[r]) + 1.f) : 0.f;
    }
#pragma unroll
    for (int nt = 0; nt < 6; ++nt) {
        int n = nt * 16 + l16;
        int c = n / CW, jj = n - c * CW;
        unsigned short* dst = hp_c + (size_t)c * NN * CW + jj;
#pragma unroll
        for (int k = 0; k < 4; ++k)
            if (r0 + k < NN) dst[(size_t)(r0 + k) * CW] = f2bu(acc[nt][k] * dv[k]);
    }
}

// ---- kernel 5: chunked gather-aggregate -> zb[i][0..96), XCD-affine ----
// One thread owns ALL 24 cols of a chunk for (node, half). Per edge per chunk:
// 1 csr load + 3x16B data loads. Adjacent lanes take contiguous halves of the
// edge range; combine via shfl_xor(1).
#define RPC2 196                // (b>>3) range; r = 2*(b>>3)+(slot&1) covers 392 rows
#define AGGB (8 * RPC2)         // 1568 blocks
__global__ __launch_bounds__(256) void k_agg(const unsigned short* __restrict__ hp_c,
                                             const int* __restrict__ off,
                                             const unsigned short* __restrict__ csr,
                                             const float* __restrict__ bg,
                                             unsigned short* __restrict__ zb) {
    const int b = blockIdx.x;
    const int slot = b & 7;
    const int c = slot >> 1;                       // chunk: pinned to XCD pair
    const int r = (b >> 3) * 2 + (slot & 1);
    const int item = r * 256 + threadIdx.x;
    if (item >= NN * 2) return;
    const int i = item >> 1;
    const int h = item & 1;                        // half (== lane parity)
    const unsigned short* __restrict__ base = hp_c + (size_t)c * NN * CW;

    float a[CW];
    if (h == 0) {  // self-loop term on even half only
        const unsigned short* sp = base + (size_t)i * CW;
        ushort8 s0 = *(const ushort8*)(sp);
        ushort8 s1 = *(const ushort8*)(sp + 8);
        ushort8 s2 = *(const ushort8*)(sp + 16);
#pragma unroll
        for (int j = 0; j < 8; ++j) {
            a[j] = bu2f(s0[j]); a[8 + j] = bu2f(s1[j]); a[16 + j] = bu2f(s2[j]);
        }
    } else {
#pragma unroll
        for (int j = 0; j < CW; ++j) a[j] = 0.f;
    }

    const int start = off[i];
    const int end = off[i + 1];
    const int len = end - start;
    const float dv = rsqrtf((float)len + 1.f);
    const int half0 = (len + 1) >> 1;
    int k = h ? start + half0 : start;
    const int ke = h ? end : start + half0;
    for (; k + 1 < ke; k += 2) {   // 2 edges x 3 loads in flight
        const unsigned short* p0 = base + (size_t)csr[k] * CW;
        const unsigned short* p1 = base + (size_t)csr[k + 1] * CW;
        ushort8 v0 = *(const ushort8*)(p0);
        ushort8 v1 = *(const ushort8*)(p0 + 8);
        ushort8 v2 = *(const ushort8*)(p0 + 16);
        ushort8 w0 = *(const ushort8*)(p1);
        ushort8 w1 = *(const ushort8*)(p1 + 8);
        ushort8 w2 = *(const ushort8*)(p1 + 16);
#pragma unroll
        for (int j = 0; j < 8; ++j) {
            a[j]      += bu2f(v0[j]) + bu2f(w0[j]);
            a[8 + j]  += bu2f(v1[j]) + bu2f(w1[j]);
            a[16 + j] += bu2f(v2[j]) + bu2f(w2[j]);
        }
    }
    if (k < ke) {
        const unsigned short* p0 = base + (size_t)csr[k] * CW;
        ushort8 v0 = *(const ushort8*)(p0);
        ushort8 v1 = *(const ushort8*)(p0 + 8);
        ushort8 v2 = *(const ushort8*)(p0 + 16);
#pragma unroll
        for (int j = 0; j < 8; ++j) {
            a[j] += bu2f(v0[j]); a[8 + j] += bu2f(v1[j]); a[16 + j] += bu2f(v2[j]);
        }
    }
#pragma unroll
    for (int j = 0; j < CW; ++j) a[j] += __shfl_xor(a[j], 1, 64);
    if (h == 0) {
        const int j0 = c * CW;
        ushort8 o0, o1, o2;
#pragma unroll
        for (int j = 0; j < 8; ++j) {
            o0[j] = f2bu(fmaxf(fmaf(dv, a[j],      bg[j0 + j]),      0.f));
            o1[j] = f2bu(fmaxf(fmaf(dv, a[8 + j],  bg[j0 + 8 + j]),  0.f));
            o2[j] = f2bu(fmaxf(fmaf(dv, a[16 + j], bg[j0 + 16 + j]), 0.f));
        }
        unsigned short* zp = zb + (size_t)i * ZK + j0;
        *(ushort8*)(zp) = o0;
        *(ushort8*)(zp + 8) = o1;
        *(ushort8*)(zp + 16) = o2;
    }
}

// ---- kernel 6: MFMA layer-1 + fused layer-2 epilogue ----
__global__ __launch_bounds__(256) void k_mlp2(const unsigned short* __restrict__ zb,
                                              const unsigned short* __restrict__ Wt1,
                                              const float* __restrict__ b1,
                                              const float* __restrict__ W2,
                                              const float* __restrict__ b2,
                                              const float* __restrict__ xw2,
                                              float* __restrict__ out) {
    const int wave = threadIdx.x >> 6;
    const int lane = threadIdx.x & 63;
    const int quad = lane >> 4;
    const int l16 = lane & 15;
    const int Mbase = blockIdx.x * 64 + wave * 16;

    const unsigned short* arow = zb + (size_t)(Mbase + l16) * ZK + quad * 8;
    const unsigned short* brow = Wt1 + (size_t)l16 * ZK + quad * 8;

    f32x4 acc[6] = {};
#pragma unroll
    for (int ks = 0; ks < 4; ++ks) {
        short8 a = *(const short8*)(arow + ks * 32);
#pragma unroll
        for (int nt = 0; nt < 6; ++nt) {
            short8 bfrag = *(const short8*)(brow + (size_t)nt * 16 * ZK + ks * 32);
            acc[nt] = __builtin_amdgcn_mfma_f32_16x16x32_bf16(a, bfrag, acc[nt], 0, 0, 0);
        }
    }
    float bb[6], wa[6];
#pragma unroll
    for (int nt = 0; nt < 6; ++nt) {
        int c = nt * 16 + l16;
        bb[nt] = b1[c];
        wa[nt] = W2[c];
    }
    const float bias2 = b2[0];

#pragma unroll
    for (int reg = 0; reg < 4; ++reg) {
        const int r = Mbase + quad * 4 + reg;
        float p = 0.f;
#pragma unroll
        for (int nt = 0; nt < 6; ++nt)
            p = fmaf(fmaxf(acc[nt][reg] + bb[nt], 0.f), wa[nt], p);
#pragma unroll
        for (int m = 1; m < 16; m <<= 1) p += __shfl_xor(p, m, 64);
        if (l16 == 0 && r < NN) out[r] = fmaxf(p + xw2[r] + bias2, 0.f);
    }
}

extern "C" void kernel_launch(void* const* d_in, const int* in_sizes, int n_in,
                              void* d_out, int out_size, void* d_ws, size_t ws_size,
                              hipStream_t stream) {
    const float* x   = (const float*)d_in[0];
    const int*   ei  = (const int*)d_in[1];
    const float* tmp = (const float*)d_in[2];
    const float* Wg  = (const float*)d_in[3];
    const float* bg  = (const float*)d_in[4];
    const float* W1  = (const float*)d_in[5];
    const float* b1  = (const float*)d_in[6];
    const float* W2  = (const float*)d_in[7];
    const float* b2  = (const float*)d_in[8];
    float* out = (float*)d_out;

    char* base = (char*)d_ws;
    int* off  = (int*)base;                                   // NN+1 ints (256KB slot)
    int* bcur = (int*)(base + (256 << 10));                   // 196 ints
    unsigned short* csr = (unsigned short*)(base + (512 << 10));       // NE ushort = 1.6MB
    unsigned short* Wt  = (unsigned short*)(base + ((size_t)3 << 20)); // NF*HH bf16
    unsigned short* Wt1 = Wt + NF * HH;                       // HH*ZK bf16
    unsigned short* hp_c = (unsigned short*)(base + ((size_t)4 << 20));  // NN*HH bf16 = 9.6MB
    unsigned short* zb  = (unsigned short*)(base + ((size_t)14 << 20));  // NPAD*ZK bf16 = 12.8MB
    float* xw2 = (float*)(base + ((size_t)27 << 20));         // NPAD floats
    int* temp  = (int*)(base + ((size_t)28 << 20));           // 196*CAP ints = 4.01MB

    k_init <<<1, 256, 0, stream>>>(bcur, off);
    k_pre  <<<FILLA_B + WBLK + W1BLK + ZTBLK + ZPBLK, 256, 0, stream>>>(
                ei, bcur, temp, Wg, W1, tmp, Wt, Wt1, zb);
    k_off  <<<NBK, 256, 0, stream>>>(temp, bcur, off);
    k_gg   <<<NBK + NPAD / 64, 256, 0, stream>>>(temp, bcur, csr, off, x, Wt, W2, hp_c, xw2);
    k_agg  <<<AGGB, 256, 0, stream>>>(hp_c, off, csr, bg, zb);
    k_mlp2 <<<NPAD / 64, 256, 0, stream>>>(zb, Wt1, b1, W2, b2, xw2, out);
}

// Round 3
// 169.086 us; speedup vs baseline: 1.1702x; 1.0290x over previous
//
#include <hip/hip_runtime.h>
#include <hip/hip_bf16.h>

#define NN 50000
#define NPAD 50048           // 64-row padded for MFMA grid
#define NE 800000
#define NF 128
#define HH 96
#define TF 10
#define Z1DIM (HH + TF)   // 106
#define ZK 128            // padded K for layer-1 MFMA
#define NCH 4             // column chunks for the gather
#define CW 24             // real cols per chunk: NCH*CW == HH
#define CWP 32            // padded row stride (64B cache line)
#define NBK 196           // dst buckets of 256 nodes
#define CAP 5120          // per-bucket temp capacity
#define EPB 4096          // edges per fillA block
#define FILLA_B ((NE + EPB - 1) / EPB)   // 196

typedef __attribute__((ext_vector_type(8))) short short8;
typedef __attribute__((ext_vector_type(8))) unsigned short ushort8;
typedef __attribute__((ext_vector_type(4))) float f32x4;

__device__ __forceinline__ float bu2f(unsigned short u) {
    union { unsigned int i; float f; } c;
    c.i = ((unsigned int)u) << 16;
    return c.f;
}
__device__ __forceinline__ unsigned short f2bu(float f) {
    union { __hip_bfloat16 h; unsigned short u; } c;
    c.h = __float2bfloat16(f);
    return c.u;
}

// ---- kernel 1: bcur[b] = b*CAP; off[NN] = NE ----
__global__ void k_init(int* __restrict__ bcur, int* __restrict__ off) {
    int t = threadIdx.x;
    if (t < NBK) bcur[t] = t * CAP;
    if (t == 255) off[NN] = NE;
}

// ---- kernel 2: fused {edge binning} | {weight transpose, zb tail} ----
#define WBLK (NF * HH / 4 / 256)       // 12
#define W1BLK (HH * ZK / 4 / 256)      // 12
#define ZTBLK (NPAD / 32)              // 1564
#define ZPBLK 5
__global__ __launch_bounds__(256) void k_pre(const int* __restrict__ ei,
                                             int* __restrict__ bcur,
                                             int* __restrict__ temp,
                                             const float* __restrict__ W,
                                             const float* __restrict__ W1,
                                             const float* __restrict__ tmp,
                                             unsigned short* __restrict__ Wt,
                                             unsigned short* __restrict__ Wt1,
                                             unsigned short* __restrict__ zb) {
    const int t = threadIdx.x;
    if (blockIdx.x < FILLA_B) {
        // ---- fillA: bin edges into 196 dst-range buckets ----
        __shared__ int hist[NBK], bas[NBK];
        for (int m = t; m < NBK; m += 256) hist[m] = 0;
        __syncthreads();
        const int e0 = blockIdx.x * EPB;
        const int ecap = min(e0 + EPB, NE);
        for (int e = e0 + t; e < ecap; e += 256) {
            int d = ei[NE + e];
            atomicAdd(&hist[d >> 8], 1);
        }
        __syncthreads();
        for (int m = t; m < NBK; m += 256) {
            int c = hist[m];
            bas[m] = c ? atomicAdd(&bcur[m], c) : 0;
            hist[m] = 0;   // reuse as run cursor
        }
        __syncthreads();
        for (int e = e0 + t; e < ecap; e += 256) {
            int d = ei[NE + e], s = ei[e];
            int b = d >> 8;
            int r = atomicAdd(&hist[b], 1);
            temp[bas[b] + r] = ((d & 255) << 16) | s;
        }
        return;
    }
    // ---- prep: Wt, Wt1, zb tail (cols 96..128 + pad rows) ----
    int b = blockIdx.x - FILLA_B;
    if (b < WBLK) {
        int e = (b * 256 + t) * 4;
        int n = e >> 7, k = e & 127;
        ushort4 v;
        v.x = f2bu(W[(k + 0) * HH + n]);
        v.y = f2bu(W[(k + 1) * HH + n]);
        v.z = f2bu(W[(k + 2) * HH + n]);
        v.w = f2bu(W[(k + 3) * HH + n]);
        *(ushort4*)(Wt + e) = v;
    } else if (b < WBLK + W1BLK) {
        int e = ((b - WBLK) * 256 + t) * 4;
        int n = e >> 7, k = e & 127;     // n in [0,96), k in [0,128)
        ushort4 v;
        v.x = (k + 0 < Z1DIM) ? f2bu(W1[(k + 0) * HH + n]) : (unsigned short)0;
        v.y = (k + 1 < Z1DIM) ? f2bu(W1[(k + 1) * HH + n]) : (unsigned short)0;
        v.z = (k + 2 < Z1DIM) ? f2bu(W1[(k + 2) * HH + n]) : (unsigned short)0;
        v.w = (k + 3 < Z1DIM) ? f2bu(W1[(k + 3) * HH + n]) : (unsigned short)0;
        *(ushort4*)(Wt1 + e) = v;
    } else if (b < WBLK + W1BLK + ZTBLK) {
        // zb cols [96,128): temporal (cc<10) else 0
        int t4 = ((b - WBLK - W1BLK) * 256 + t) * 4;
        int i = t4 >> 5, cc = t4 & 31;
        ushort4 v; v.x = v.y = v.z = v.w = 0;
        if (i < NN) {
            if (cc + 0 < TF) v.x = f2bu(tmp[(size_t)i * TF + cc + 0]);
            if (cc + 1 < TF) v.y = f2bu(tmp[(size_t)i * TF + cc + 1]);
            if (cc + 2 < TF) v.z = f2bu(tmp[(size_t)i * TF + cc + 2]);
            if (cc + 3 < TF) v.w = f2bu(tmp[(size_t)i * TF + cc + 3]);
        }
        *(ushort4*)(zb + (size_t)i * ZK + HH + cc) = v;
    } else {
        // zb pad rows [NN,NPAD), cols [0,96): zero
        int t4 = ((b - WBLK - W1BLK - ZTBLK) * 256 + t) * 4;
        if (t4 < (NPAD - NN) * HH) {
            int i = NN + t4 / HH, j = t4 % HH;
            ushort4 z; z.x = z.y = z.z = z.w = 0;
            *(ushort4*)(zb + (size_t)i * ZK + j) = z;
        }
    }
}

// ---- kernel 3: per-bucket histogram + scans -> off[] only ----
__global__ __launch_bounds__(256) void k_off(const int* __restrict__ temp,
                                             const int* __restrict__ bcur,
                                             int* __restrict__ off) {
    __shared__ int ls[256], lc[256];
    const int b = blockIdx.x, t = threadIdx.x;
    int szt = (t < NBK) ? (bcur[t] - t * CAP) : 0;
    ls[t] = szt;
    __syncthreads();
#pragma unroll
    for (int d = 1; d < 256; d <<= 1) {
        int u = (t >= d) ? ls[t - d] : 0;
        __syncthreads();
        ls[t] += u;
        __syncthreads();
    }
    const int g0 = (b > 0) ? ls[b - 1] : 0;
    __syncthreads();
    ls[t] = 0;
    __syncthreads();
    const int seg0 = b * CAP;
    const int m = bcur[b] - seg0;
    for (int k = t; k < m; k += 256) atomicAdd(&ls[temp[seg0 + k] >> 16], 1);
    __syncthreads();
    const int myc = ls[t];
    lc[t] = myc;
    __syncthreads();
#pragma unroll
    for (int d = 1; d < 256; d <<= 1) {
        int u = (t >= d) ? lc[t - d] : 0;
        __syncthreads();
        lc[t] += u;
        __syncthreads();
    }
    const int i = b * 256 + t;
    if (i < NN) off[i] = g0 + lc[t] - myc;
}

// ---- kernel 4: fused {csr scatter-sort} | {MFMA GEMM + x·W2 row-dot} ----
__global__ __launch_bounds__(256) void k_gg(const int* __restrict__ temp,
                                            const int* __restrict__ bcur,
                                            unsigned short* __restrict__ csr,
                                            const int* __restrict__ off,
                                            const float* __restrict__ x,
                                            const unsigned short* __restrict__ Wt,
                                            const float* __restrict__ W2,
                                            unsigned short* __restrict__ hp_c,
                                            float* __restrict__ xw2) {
    const int t = threadIdx.x;
    if (blockIdx.x < NBK) {
        // ---- sort: scatter bucket entries to csr at absolute cursors off[i] ----
        __shared__ int lc[256];
        const int b = blockIdx.x;
        const int i = b * 256 + t;
        lc[t] = (i < NN) ? off[i] : 0;
        __syncthreads();
        const int seg0 = b * CAP;
        const int m = bcur[b] - seg0;
        for (int k = t; k < m; k += 256) {
            int v = temp[seg0 + k];
            int r = atomicAdd(&lc[v >> 16], 1);
            csr[r] = (unsigned short)(v & 0xFFFF);
        }
        return;
    }
    // ---- gemm: h = bf16(x)·Wt scaled by rsqrt(deg+1), + fused x·W2[96:224] ----
    const int wave = t >> 6;
    const int lane = t & 63;
    const int quad = lane >> 4;
    const int l16 = lane & 15;
    const int Mbase = (blockIdx.x - NBK) * 64 + wave * 16;
    const int row = Mbase + l16;
    const bool valid = row < NN;

    const float* xr = x + (size_t)row * NF + quad * 8;
    const unsigned short* brow = Wt + (size_t)l16 * NF + quad * 8;

    f32x4 acc[6] = {};
    float xs = 0.f;
#pragma unroll
    for (int ks = 0; ks < 4; ++ks) {
        short8 a = {};
        if (valid) {
            float4 f0 = *(const float4*)(xr + ks * 32);
            float4 f1 = *(const float4*)(xr + ks * 32 + 4);
            const float4 w0 = *(const float4*)(W2 + HH + quad * 8 + ks * 32);
            const float4 w1 = *(const float4*)(W2 + HH + quad * 8 + ks * 32 + 4);
            xs = fmaf(f0.x, w0.x, xs); xs = fmaf(f0.y, w0.y, xs);
            xs = fmaf(f0.z, w0.z, xs); xs = fmaf(f0.w, w0.w, xs);
            xs = fmaf(f1.x, w1.x, xs); xs = fmaf(f1.y, w1.y, xs);
            xs = fmaf(f1.z, w1.z, xs); xs = fmaf(f1.w, w1.w, xs);
            a[0] = (short)f2bu(f0.x); a[1] = (short)f2bu(f0.y);
            a[2] = (short)f2bu(f0.z); a[3] = (short)f2bu(f0.w);
            a[4] = (short)f2bu(f1.x); a[5] = (short)f2bu(f1.y);
            a[6] = (short)f2bu(f1.z); a[7] = (short)f2bu(f1.w);
        }
#pragma unroll
        for (int nt = 0; nt < 6; ++nt) {
            short8 bfrag = *(const short8*)(brow + (size_t)nt * 16 * NF + ks * 32);
            acc[nt] = __builtin_amdgcn_mfma_f32_16x16x32_bf16(a, bfrag, acc[nt], 0, 0, 0);
        }
    }
    xs += __shfl_xor(xs, 16, 64);
    xs += __shfl_xor(xs, 32, 64);
    if (quad == 0 && valid) xw2[row] = xs;

    const int r0 = Mbase + quad * 4;
    float dv[4];
#pragma unroll
    for (int k = 0; k < 4; ++k) {
        int r = r0 + k;
        dv[k] = (r < NN) ? rsqrtf((float)(off[r + 1] - off[r]) + 1.f) : 0.f;
    }
#pragma unroll
    for (int nt = 0; nt < 6; ++nt) {
        int n = nt * 16 + l16;
        int c = n / CW, jj = n - c * CW;
        unsigned short* dst = hp_c + (size_t)c * NN * CWP + jj;
#pragma unroll
        for (int k = 0; k < 4; ++k)
            if (r0 + k < NN) dst[(size_t)(r0 + k) * CWP] = f2bu(acc[nt][k] * dv[k]);
    }
}

// ---- kernel 5: chunked gather-aggregate -> zb[i][0..96), XCD-affine ----
// 4 adjacent lanes (q=0..3) cooperatively load one 64B hp_c row per edge:
// one fully-used cache line per edge*chunk (was 3 lines @ 25% use).
// 2 halves (h) split the edge list; combine via shfl_xor(4).
// q==3 covers the 8 pad cols (garbage accumulated, never written).
#define AGGB (8 * 782)          // r=(b>>3)*2+(slot&1) in [0,1564); items NN*8 per chunk
__global__ __launch_bounds__(256) void k_agg(const unsigned short* __restrict__ hp_c,
                                             const int* __restrict__ off,
                                             const unsigned short* __restrict__ csr,
                                             const float* __restrict__ bg,
                                             unsigned short* __restrict__ zb) {
    const int b = blockIdx.x;
    const int slot = b & 7;
    const int c = slot >> 1;                       // chunk: pinned to XCD pair
    const int r = (b >> 3) * 2 + (slot & 1);
    const int item = r * 256 + threadIdx.x;
    if (item >= NN * 8) return;
    const int i = item >> 3;
    const int sub = item & 7;
    const int q = sub & 3;                         // 16B quarter of the 64B row
    const int h = sub >> 2;                        // edge-range half
    const int q8 = q * 8;
    const unsigned short* __restrict__ base = hp_c + (size_t)c * NN * CWP + q8;

    float a[8];
    if (h == 0) {  // self-loop term on h==0 only
        ushort8 sv = *(const ushort8*)(base + (size_t)i * CWP);
#pragma unroll
        for (int j = 0; j < 8; ++j) a[j] = bu2f(sv[j]);
    } else {
#pragma unroll
        for (int j = 0; j < 8; ++j) a[j] = 0.f;
    }

    const int start = off[i];
    const int end = off[i + 1];
    const int len = end - start;
    const float dv = rsqrtf((float)len + 1.f);
    const int half0 = (len + 1) >> 1;
    int k = h ? start + half0 : start;
    const int ke = h ? end : start + half0;
    for (; k + 3 < ke; k += 4) {   // 4 edges x 1 line each in flight
        int s0 = csr[k], s1 = csr[k + 1], s2 = csr[k + 2], s3 = csr[k + 3];
        ushort8 v0 = *(const ushort8*)(base + (size_t)s0 * CWP);
        ushort8 v1 = *(const ushort8*)(base + (size_t)s1 * CWP);
        ushort8 v2 = *(const ushort8*)(base + (size_t)s2 * CWP);
        ushort8 v3 = *(const ushort8*)(base + (size_t)s3 * CWP);
#pragma unroll
        for (int j = 0; j < 8; ++j)
            a[j] += (bu2f(v0[j]) + bu2f(v1[j])) + (bu2f(v2[j]) + bu2f(v3[j]));
    }
    for (; k < ke; ++k) {
        ushort8 v0 = *(const ushort8*)(base + (size_t)csr[k] * CWP);
#pragma unroll
        for (int j = 0; j < 8; ++j) a[j] += bu2f(v0[j]);
    }
#pragma unroll
    for (int j = 0; j < 8; ++j) a[j] += __shfl_xor(a[j], 4, 64);
    if (h == 0 && q < 3) {
        const int j0 = c * CW + q8;
        ushort8 o;
#pragma unroll
        for (int j = 0; j < 8; ++j)
            o[j] = f2bu(fmaxf(fmaf(dv, a[j], bg[j0 + j]), 0.f));
        *(ushort8*)(zb + (size_t)i * ZK + j0) = o;
    }
}

// ---- kernel 6: MFMA layer-1 + fused layer-2 epilogue ----
__global__ __launch_bounds__(256) void k_mlp2(const unsigned short* __restrict__ zb,
                                              const unsigned short* __restrict__ Wt1,
                                              const float* __restrict__ b1,
                                              const float* __restrict__ W2,
                                              const float* __restrict__ b2,
                                              const float* __restrict__ xw2,
                                              float* __restrict__ out) {
    const int wave = threadIdx.x >> 6;
    const int lane = threadIdx.x & 63;
    const int quad = lane >> 4;
    const int l16 = lane & 15;
    const int Mbase = blockIdx.x * 64 + wave * 16;

    const unsigned short* arow = zb + (size_t)(Mbase + l16) * ZK + quad * 8;
    const unsigned short* brow = Wt1 + (size_t)l16 * ZK + quad * 8;

    f32x4 acc[6] = {};
#pragma unroll
    for (int ks = 0; ks < 4; ++ks) {
        short8 a = *(const short8*)(arow + ks * 32);
#pragma unroll
        for (int nt = 0; nt < 6; ++nt) {
            short8 bfrag = *(const short8*)(brow + (size_t)nt * 16 * ZK + ks * 32);
            acc[nt] = __builtin_amdgcn_mfma_f32_16x16x32_bf16(a, bfrag, acc[nt], 0, 0, 0);
        }
    }
    float bb[6], wa[6];
#pragma unroll
    for (int nt = 0; nt < 6; ++nt) {
        int c = nt * 16 + l16;
        bb[nt] = b1[c];
        wa[nt] = W2[c];
    }
    const float bias2 = b2[0];

#pragma unroll
    for (int reg = 0; reg < 4; ++reg) {
        const int r = Mbase + quad * 4 + reg;
        float p = 0.f;
#pragma unroll
        for (int nt = 0; nt < 6; ++nt)
            p = fmaf(fmaxf(acc[nt][reg] + bb[nt], 0.f), wa[nt], p);
#pragma unroll
        for (int m = 1; m < 16; m <<= 1) p += __shfl_xor(p, m, 64);
        if (l16 == 0 && r < NN) out[r] = fmaxf(p + xw2[r] + bias2, 0.f);
    }
}

extern "C" void kernel_launch(void* const* d_in, const int* in_sizes, int n_in,
                              void* d_out, int out_size, void* d_ws, size_t ws_size,
                              hipStream_t stream) {
    const float* x   = (const float*)d_in[0];
    const int*   ei  = (const int*)d_in[1];
    const float* tmp = (const float*)d_in[2];
    const float* Wg  = (const float*)d_in[3];
    const float* bg  = (const float*)d_in[4];
    const float* W1  = (const float*)d_in[5];
    const float* b1  = (const float*)d_in[6];
    const float* W2  = (const float*)d_in[7];
    const float* b2  = (const float*)d_in[8];
    float* out = (float*)d_out;

    char* base = (char*)d_ws;
    int* off  = (int*)base;                                   // NN+1 ints (256KB slot)
    int* bcur = (int*)(base + (256 << 10));                   // 196 ints
    unsigned short* csr = (unsigned short*)(base + (512 << 10));       // NE ushort = 1.6MB
    unsigned short* Wt  = (unsigned short*)(base + ((size_t)3 << 20)); // NF*HH bf16
    unsigned short* Wt1 = Wt + NF * HH;                       // HH*ZK bf16
    unsigned short* hp_c = (unsigned short*)(base + ((size_t)4 << 20));  // 4*NN*CWP bf16 = 12.8MB
    unsigned short* zb  = (unsigned short*)(base + ((size_t)17 << 20));  // NPAD*ZK bf16 = 12.8MB
    float* xw2 = (float*)(base + ((size_t)30 << 20));         // NPAD floats
    int* temp  = (int*)(base + ((size_t)31 << 20));           // 196*CAP ints = 4.01MB

    k_init <<<1, 256, 0, stream>>>(bcur, off);
    k_pre  <<<FILLA_B + WBLK + W1BLK + ZTBLK + ZPBLK, 256, 0, stream>>>(
                ei, bcur, temp, Wg, W1, tmp, Wt, Wt1, zb);
    k_off  <<<NBK, 256, 0, stream>>>(temp, bcur, off);
    k_gg   <<<NBK + NPAD / 64, 256, 0, stream>>>(temp, bcur, csr, off, x, Wt, W2, hp_c, xw2);
    k_agg  <<<AGGB, 256, 0, stream>>>(hp_c, off, csr, bg, zb);
    k_mlp2 <<<NPAD / 64, 256, 0, stream>>>(zb, Wt1, b1, W2, b2, xw2, out);
}